// Round 3
// baseline (4962.217 us; speedup 1.0000x reference)
//
#include <hip/hip_runtime.h>
#include <hip/hip_bf16.h>

#define NB 8192
#define NT 50
#define EPG 4   // batch elements per 32-lane group

__device__ __forceinline__ float leaky(float x) { return x > 0.0f ? x : 0.3f * x; }

__device__ __forceinline__ float idm_act_f(float v, float dv, float dx,
                                           float inv_v0, float tg, float jam,
                                           float amax, float inv_gd) {
    dx = fminf(fmaxf(dx, 0.1f), 500.0f);
    float gap = tg * v + v * dv * inv_gd;
    float dg = jam + fmaxf(gap, 0.0f);
    float r = v * inv_v0;
    float r2 = r * r;
    float r4 = r2 * r2;
    float q = dg / dx;
    float act = amax * (1.0f - r4 - q * q);
    return fminf(fmaxf(act, -6.0f), 6.0f);
}

extern "C" __global__ __launch_bounds__(256, 1)
void idm_rollout_kernel(const float* __restrict__ idm_params,
                        const float* __restrict__ proj_latent,
                        const float* __restrict__ enc_h,
                        const float* __restrict__ idm_s,
                        const float* __restrict__ merger_cs,
                        const float* __restrict__ scaler_mean,
                        const float* __restrict__ scaler_var,
                        const float* __restrict__ W1,
                        const float* __restrict__ b1,
                        const float* __restrict__ W2,
                        const float* __restrict__ b2,
                        const float* __restrict__ Wf,
                        const float* __restrict__ bfp,
                        const float* __restrict__ Wm,
                        const float* __restrict__ bmp,
                        float* __restrict__ out)
{
    __shared__ float s_w2[128 * 128];      // [k][j]
    __shared__ float s_w1e[8 * 128];       // env rows, inv_std folded
    __shared__ float s_w1m[3 * 128];       // mc rows
    __shared__ float s_pk[8][EPG][132];    // per-group h1 pack [e][k]

    const int tid = threadIdx.x;

    // ---- stage weights into LDS ----
    {
        const float4* src = (const float4*)W2;
        float4* dst = (float4*)s_w2;
        #pragma unroll
        for (int i = 0; i < 16; ++i) dst[tid + 256 * i] = src[tid + 256 * i];
    }
    {   // 8 env rows of W1 (rows 256..263), scale by 1/sqrt(var[k])
        const int k = tid >> 5;
        const float is = 1.0f / sqrtf(scaler_var[k]);
        const float4 w = *(const float4*)&W1[(256 + k) * 128 + ((tid << 2) & 127)];
        float4 o; o.x = w.x * is; o.y = w.y * is; o.z = w.z * is; o.w = w.w * is;
        *(float4*)&s_w1e[tid << 2] = o;
    }
    if (tid < 96) {   // 3 mc rows of W1 (rows 264..266)
        const int k = tid >> 5;
        const int j = (tid << 2) & 127;
        *(float4*)&s_w1m[tid << 2] = *(const float4*)&W1[(264 + k) * 128 + j];
    }
    __syncthreads();

    // ---- lane geometry: 32 lanes per group, EPG elems per group ----
    const int sidx = tid & 31;            // column-slice within group
    const int g    = tid >> 5;            // 0..7 group in block
    const int jq   = sidx * 4;            // this lane's column quad
    const int b0   = blockIdx.x * (8 * EPG) + g * EPG;   // first elem of group
    float (*pk)[132] = s_pk[g];

    // ---- per-elem params ----
    float inv_v0[EPG], p_tg[EPG], p_jam[EPG], p_amax[EPG], inv_gd[EPG];
    #pragma unroll
    for (int e = 0; e < EPG; ++e) {
        const int b = b0 + e;
        const float v0 = idm_params[b * 5 + 0];
        p_tg[e]   = idm_params[b * 5 + 1];
        p_jam[e]  = idm_params[b * 5 + 2];
        p_amax[e] = idm_params[b * 5 + 3];
        const float amin = idm_params[b * 5 + 4];
        inv_v0[e] = 1.0f / v0;
        inv_gd[e] = 1.0f / (2.0f * sqrtf(p_amax[e] * amin));
    }

    // ---- per-lane weight quads ----
    const float4 wfq = *(const float4*)&Wf[jq];
    const float4 wmq = *(const float4*)&Wm[jq];
    const float4 b2q = *(const float4*)&b2[jq];
    const float bfv = bfp[0];
    const float bmv = bmp[0];

    // ---- hpre: time-invariant part of layer-1 preactivation ----
    float4 hp[EPG];
    {
        const float4 b1q = *(const float4*)&b1[jq];
        #pragma unroll
        for (int e = 0; e < EPG; ++e) hp[e] = b1q;
    }
    #pragma unroll 2
    for (int kk = 0; kk < 128; kk += 4) {
        float4 w[4];
        #pragma unroll
        for (int i = 0; i < 4; ++i) w[i] = *(const float4*)&W1[(kk + i) * 128 + jq];
        #pragma unroll
        for (int e = 0; e < EPG; ++e) {
            const float4 x = *(const float4*)&proj_latent[(size_t)(b0 + e) * 128 + kk];
            hp[e].x += x.x * w[0].x + x.y * w[1].x + x.z * w[2].x + x.w * w[3].x;
            hp[e].y += x.x * w[0].y + x.y * w[1].y + x.z * w[2].y + x.w * w[3].y;
            hp[e].z += x.x * w[0].z + x.y * w[1].z + x.z * w[2].z + x.w * w[3].z;
            hp[e].w += x.x * w[0].w + x.y * w[1].w + x.z * w[2].w + x.w * w[3].w;
        }
    }
    #pragma unroll 2
    for (int kk = 0; kk < 128; kk += 4) {
        float4 w[4];
        #pragma unroll
        for (int i = 0; i < 4; ++i) w[i] = *(const float4*)&W1[(128 + kk + i) * 128 + jq];
        #pragma unroll
        for (int e = 0; e < EPG; ++e) {
            const float4 x = *(const float4*)&enc_h[(size_t)(b0 + e) * 128 + kk];
            hp[e].x += x.x * w[0].x + x.y * w[1].x + x.z * w[2].x + x.w * w[3].x;
            hp[e].y += x.x * w[0].y + x.y * w[1].y + x.z * w[2].y + x.w * w[3].y;
            hp[e].z += x.x * w[0].z + x.y * w[1].z + x.z * w[2].z + x.w * w[3].z;
            hp[e].w += x.x * w[0].w + x.y * w[1].w + x.z * w[2].w + x.w * w[3].w;
        }
    }
    // fold -(mean*inv_std) @ W1env into hpre (s_w1e already has inv_std)
    #pragma unroll
    for (int k = 0; k < 8; ++k) {
        const float mk = scaler_mean[k];
        const float4 w = *(const float4*)&s_w1e[k * 128 + jq];
        #pragma unroll
        for (int e = 0; e < EPG; ++e) {
            hp[e].x -= mk * w.x; hp[e].y -= mk * w.y;
            hp[e].z -= mk * w.z; hp[e].w -= mk * w.w;
        }
    }

    // ---- carry init ----
    const float* srow[EPG];
    const float* mrow[EPG];
    float ego_v[EPG], ego_a[EPG], ego_x[EPG], disp[EPG];
    #pragma unroll
    for (int e = 0; e < EPG; ++e) {
        const int b = b0 + e;
        srow[e] = idm_s + (size_t)b * 714;    // 51*14
        mrow[e] = merger_cs + (size_t)b * 150;
        ego_v[e] = srow[e][0];
        ego_a[e] = srow[e][11];
        ego_x[e] = srow[e][3];
        disp[e]  = 0.0f;
    }

    float* out_disp = out;
    float* out_act  = out + NB * 51;
    float* out_fat  = out + NB * (51 + 50);
    float* out_mat  = out + NB * (51 + 100);
    if (sidx == 0) {
        #pragma unroll
        for (int e = 0; e < EPG; ++e) out_disp[(b0 + e) * 51] = 0.0f;
    }

    // prefetch t=0 scalars
    float c_fv[EPG], c_mv[EPG], c_fx[EPG], c_mx[EPG], c_fa[EPG], c_me[EPG];
    float c_m0[EPG], c_m1[EPG], c_m2[EPG];
    #pragma unroll
    for (int e = 0; e < EPG; ++e) {
        c_fv[e] = srow[e][1];  c_mv[e] = srow[e][2];
        c_fx[e] = srow[e][4];  c_mx[e] = srow[e][5];
        c_fa[e] = srow[e][12]; c_me[e] = srow[e][13];
        c_m0[e] = mrow[e][0];  c_m1[e] = mrow[e][1]; c_m2[e] = mrow[e][2];
    }

    for (int t = 0; t < NT; ++t) {
        float fv[EPG], mv[EPG], fx[EPG], mx[EPG], fa[EPG], me[EPG];
        float m0[EPG], m1[EPG], m2[EPG];
        #pragma unroll
        for (int e = 0; e < EPG; ++e) {
            fv[e] = c_fv[e]; mv[e] = c_mv[e]; fx[e] = c_fx[e]; mx[e] = c_mx[e];
            fa[e] = c_fa[e]; me[e] = c_me[e];
            m0[e] = c_m0[e]; m1[e] = c_m1[e]; m2[e] = c_m2[e];
        }
        if (t + 1 < NT) {
            #pragma unroll
            for (int e = 0; e < EPG; ++e) {
                const float* sp = srow[e] + (t + 1) * 14;
                c_fv[e] = sp[1]; c_mv[e] = sp[2]; c_fx[e] = sp[4]; c_mx[e] = sp[5];
                c_fa[e] = sp[12]; c_me[e] = sp[13];
                const float* mp = mrow[e] + (t + 1) * 3;
                c_m0[e] = mp[0]; c_m1[e] = mp[1]; c_m2[e] = mp[2];
            }
        }

        float ef_dx[EPG], em_dx[EPG], ef_dv[EPG], em_dv[EPG];
        float4 h1[EPG];
        #pragma unroll
        for (int e = 0; e < EPG; ++e) {
            ef_dx[e] = fx[e] - ego_x[e];
            em_dx[e] = (mx[e] - ego_x[e]) * me[e] + (1.0f - me[e]) * 100.0f;
            ef_dv[e] = ego_v[e] - fv[e];
            em_dv[e] = (ego_v[e] - mv[e]) * me[e];
            h1[e] = hp[e];
        }

        // ---- layer 1: 8 env rows + 3 mc rows ----
        #pragma unroll
        for (int k = 0; k < 8; ++k) {
            const float4 w = *(const float4*)&s_w1e[k * 128 + jq];
            #pragma unroll
            for (int e = 0; e < EPG; ++e) {
                float x;
                switch (k) {
                    case 0: x = ego_a[e]; break;
                    case 1: x = fa[e];    break;
                    case 2: x = ego_v[e]; break;
                    case 3: x = fv[e];    break;
                    case 4: x = ef_dv[e]; break;
                    case 5: x = ef_dx[e]; break;
                    case 6: x = em_dv[e]; break;
                    default: x = em_dx[e]; break;
                }
                h1[e].x += x * w.x; h1[e].y += x * w.y;
                h1[e].z += x * w.z; h1[e].w += x * w.w;
            }
        }
        #pragma unroll
        for (int k = 0; k < 3; ++k) {
            const float4 w = *(const float4*)&s_w1m[k * 128 + jq];
            #pragma unroll
            for (int e = 0; e < EPG; ++e) {
                const float x = (k == 0) ? m0[e] : (k == 1) ? m1[e] : m2[e];
                h1[e].x += x * w.x; h1[e].y += x * w.y;
                h1[e].z += x * w.z; h1[e].w += x * w.w;
            }
        }
        #pragma unroll
        for (int e = 0; e < EPG; ++e) {
            h1[e].x = leaky(h1[e].x); h1[e].y = leaky(h1[e].y);
            h1[e].z = leaky(h1[e].z); h1[e].w = leaky(h1[e].w);
            *(float4*)&pk[e][jq] = h1[e];   // [e][k] pack, contiguous 512B sweep
        }
        asm volatile("" ::: "memory");      // intra-wave DS is in-order; block reorder

        // ---- layer 2: h2 = leaky(h1 @ W2 + b2), 4 cols x 4 elems per lane ----
        float4 acc[EPG];
        #pragma unroll
        for (int e = 0; e < EPG; ++e) acc[e] = make_float4(0.f, 0.f, 0.f, 0.f);
        #pragma unroll
        for (int kk = 0; kk < 128; kk += 4) {
            float4 w[4];
            #pragma unroll
            for (int i = 0; i < 4; ++i) w[i] = *(const float4*)&s_w2[(kk + i) * 128 + jq];
            #pragma unroll
            for (int e = 0; e < EPG; ++e) {
                const float4 he = *(const float4*)&pk[e][kk];   // group-uniform broadcast
                acc[e].x += he.x * w[0].x + he.y * w[1].x + he.z * w[2].x + he.w * w[3].x;
                acc[e].y += he.x * w[0].y + he.y * w[1].y + he.z * w[2].y + he.w * w[3].y;
                acc[e].z += he.x * w[0].z + he.y * w[1].z + he.z * w[2].z + he.w * w[3].z;
                acc[e].w += he.x * w[0].w + he.y * w[1].w + he.z * w[2].w + he.w * w[3].w;
            }
        }

        // heads + per-elem dynamics
        #pragma unroll
        for (int e = 0; e < EPG; ++e) {
            const float h20 = leaky(acc[e].x + b2q.x);
            const float h21 = leaky(acc[e].y + b2q.y);
            const float h22 = leaky(acc[e].z + b2q.z);
            const float h23 = leaky(acc[e].w + b2q.w);

            float fp = h20 * wfq.x + h21 * wfq.y + h22 * wfq.z + h23 * wfq.w;
            float mq = h20 * wmq.x + h21 * wmq.y + h22 * wmq.z + h23 * wmq.w;
            fp += __shfl_xor(fp, 1); fp += __shfl_xor(fp, 2);
            fp += __shfl_xor(fp, 4); fp += __shfl_xor(fp, 8); fp += __shfl_xor(fp, 16);
            mq += __shfl_xor(mq, 1); mq += __shfl_xor(mq, 2);
            mq += __shfl_xor(mq, 4); mq += __shfl_xor(mq, 8); mq += __shfl_xor(mq, 16);

            const float f_sc = fminf(fmaxf(fp + bfv, -20.0f), 20.0f);
            const float m_sc = fminf(fmaxf(mq + bmv, -20.0f), 20.0f);
            const float dsc = 5.0f * (f_sc - m_sc);
            float fatt;
            if (dsc >= 0.0f) { const float ex = __expf(-dsc); fatt = 1.0f / (1.0f + ex); }
            else             { const float ex = __expf(dsc);  fatt = ex / (1.0f + ex); }
            const float matt = 1.0f - fatt;

            const float efa = idm_act_f(ego_v[e], ef_dv[e], ef_dx[e],
                                        inv_v0[e], p_tg[e], p_jam[e], p_amax[e], inv_gd[e]);
            const float ema = idm_act_f(ego_v[e], em_dv[e], em_dx[e],
                                        inv_v0[e], p_tg[e], p_jam[e], p_amax[e], inv_gd[e]);
            const float a2n = fatt * efa + matt * ema;

            const float delta = ego_v[e] * 0.1f + 0.005f * a2n;
            disp[e]  += delta;
            ego_x[e] += delta;
            ego_v[e] += a2n * 0.1f;
            ego_a[e]  = a2n;

            if (sidx == 0) {
                const int b = b0 + e;
                out_disp[b * 51 + t + 1] = disp[e];
                out_act [b * 50 + t]     = a2n;
                out_fat [b * 50 + t]     = fatt;
                out_mat [b * 50 + t]     = matt;
            }
        }
    }
}

extern "C" void kernel_launch(void* const* d_in, const int* in_sizes, int n_in,
                              void* d_out, int out_size, void* d_ws, size_t ws_size,
                              hipStream_t stream) {
    (void)in_sizes; (void)n_in; (void)d_ws; (void)ws_size; (void)out_size;
    const float* idm_params  = (const float*)d_in[0];
    const float* proj_latent = (const float*)d_in[1];
    const float* enc_h       = (const float*)d_in[2];
    const float* idm_s       = (const float*)d_in[3];
    const float* merger_cs   = (const float*)d_in[4];
    const float* scaler_mean = (const float*)d_in[5];
    const float* scaler_var  = (const float*)d_in[6];
    const float* W1          = (const float*)d_in[7];
    const float* b1          = (const float*)d_in[8];
    const float* W2          = (const float*)d_in[9];
    const float* b2          = (const float*)d_in[10];
    const float* Wf          = (const float*)d_in[11];
    const float* bfp         = (const float*)d_in[12];
    const float* Wm          = (const float*)d_in[13];
    const float* bmp         = (const float*)d_in[14];

    idm_rollout_kernel<<<dim3(NB / (8 * EPG)), dim3(256), 0, stream>>>(
        idm_params, proj_latent, enc_h, idm_s, merger_cs,
        scaler_mean, scaler_var, W1, b1, W2, b2, Wf, bfp, Wm, bmp,
        (float*)d_out);
}

// Round 4
// 341.459 us; speedup vs baseline: 14.5324x; 14.5324x over previous
//
#include <hip/hip_runtime.h>

#define NB 8192
#define NT 50
#define EPG 2   // batch elements per 32-lane group

typedef float v4 __attribute__((ext_vector_type(4)));

__device__ __forceinline__ v4 splat4(float x) { v4 r = {x, x, x, x}; return r; }
__device__ __forceinline__ float leaky(float x) { return x > 0.0f ? x : 0.3f * x; }
__device__ __forceinline__ v4 leaky4(v4 x) {
    v4 r; r.x = leaky(x.x); r.y = leaky(x.y); r.z = leaky(x.z); r.w = leaky(x.w);
    return r;
}

__device__ __forceinline__ float idm_act_f(float v, float dv, float dx,
                                           float inv_v0, float tg, float jam,
                                           float amax, float inv_gd) {
    dx = fminf(fmaxf(dx, 0.1f), 500.0f);
    float gap = tg * v + v * dv * inv_gd;
    float dg = jam + fmaxf(gap, 0.0f);
    float r = v * inv_v0;
    float r2 = r * r;
    float r4 = r2 * r2;
    float q = dg / dx;
    float act = amax * (1.0f - r4 - q * q);
    return fminf(fmaxf(act, -6.0f), 6.0f);
}

extern "C" __global__ __launch_bounds__(256, 2)
void idm_rollout_kernel(const float* __restrict__ idm_params,
                        const float* __restrict__ proj_latent,
                        const float* __restrict__ enc_h,
                        const float* __restrict__ idm_s,
                        const float* __restrict__ merger_cs,
                        const float* __restrict__ scaler_mean,
                        const float* __restrict__ scaler_var,
                        const float* __restrict__ W1,
                        const float* __restrict__ b1,
                        const float* __restrict__ W2,
                        const float* __restrict__ b2,
                        const float* __restrict__ Wf,
                        const float* __restrict__ bfp,
                        const float* __restrict__ Wm,
                        const float* __restrict__ bmp,
                        float* __restrict__ out)
{
    __shared__ float s_w2[128 * 128];      // [k][j]
    __shared__ float s_w1e[8 * 128];       // env rows, inv_std folded
    __shared__ float s_w1m[3 * 128];       // mc rows
    __shared__ float s_pk[8][EPG][132];    // per-group h1 pack

    const int tid = threadIdx.x;

    // ---- stage weights into LDS ----
    {
        const float4* src = (const float4*)W2;
        float4* dst = (float4*)s_w2;
        #pragma unroll
        for (int i = 0; i < 16; ++i) dst[tid + 256 * i] = src[tid + 256 * i];
    }
    {   // 8 env rows of W1 (rows 256..263), scale by 1/sqrt(var[k])
        const int k = tid >> 5;
        const float is = 1.0f / sqrtf(scaler_var[k]);
        const float4 w = *(const float4*)&W1[(256 + k) * 128 + ((tid << 2) & 127)];
        float4 o; o.x = w.x * is; o.y = w.y * is; o.z = w.z * is; o.w = w.w * is;
        *(float4*)&s_w1e[tid << 2] = o;
    }
    if (tid < 96) {   // 3 mc rows of W1 (rows 264..266)
        const int k = tid >> 5;
        const int j = (tid << 2) & 127;
        *(float4*)&s_w1m[tid << 2] = *(const float4*)&W1[(264 + k) * 128 + j];
    }
    __syncthreads();

    // ---- lane geometry: 32 lanes per group, EPG elems per group ----
    const int sidx = tid & 31;            // column-slice within group
    const int g    = tid >> 5;            // 0..7 group in block
    const int jq   = sidx * 4;            // this lane's column quad
    const int b0   = blockIdx.x * (8 * EPG) + g * EPG;

    // ---- per-elem params ----
    float inv_v0[EPG], p_tg[EPG], p_jam[EPG], p_amax[EPG], inv_gd[EPG];
    #pragma unroll
    for (int e = 0; e < EPG; ++e) {
        const int b = b0 + e;
        const float v0 = idm_params[b * 5 + 0];
        p_tg[e]   = idm_params[b * 5 + 1];
        p_jam[e]  = idm_params[b * 5 + 2];
        p_amax[e] = idm_params[b * 5 + 3];
        const float amin = idm_params[b * 5 + 4];
        inv_v0[e] = 1.0f / v0;
        inv_gd[e] = 1.0f / (2.0f * sqrtf(p_amax[e] * amin));
    }

    // ---- per-lane weight quads ----
    const v4 wfq = *(const v4*)&Wf[jq];
    const v4 wmq = *(const v4*)&Wm[jq];
    const v4 b2q = *(const v4*)&b2[jq];
    const float bfv = bfp[0];
    const float bmv = bmp[0];

    // ---- hpre: time-invariant part of layer-1 preactivation ----
    v4 hp[EPG];
    {
        const v4 b1q = *(const v4*)&b1[jq];
        #pragma unroll
        for (int e = 0; e < EPG; ++e) hp[e] = b1q;
    }
    #pragma unroll 2
    for (int kk = 0; kk < 128; kk += 4) {
        v4 w0 = *(const v4*)&W1[(kk + 0) * 128 + jq];
        v4 w1 = *(const v4*)&W1[(kk + 1) * 128 + jq];
        v4 w2 = *(const v4*)&W1[(kk + 2) * 128 + jq];
        v4 w3 = *(const v4*)&W1[(kk + 3) * 128 + jq];
        #pragma unroll
        for (int e = 0; e < EPG; ++e) {
            const v4 x = *(const v4*)&proj_latent[(size_t)(b0 + e) * 128 + kk];
            hp[e] += splat4(x.x) * w0 + splat4(x.y) * w1
                   + splat4(x.z) * w2 + splat4(x.w) * w3;
        }
    }
    #pragma unroll 2
    for (int kk = 0; kk < 128; kk += 4) {
        v4 w0 = *(const v4*)&W1[(128 + kk + 0) * 128 + jq];
        v4 w1 = *(const v4*)&W1[(128 + kk + 1) * 128 + jq];
        v4 w2 = *(const v4*)&W1[(128 + kk + 2) * 128 + jq];
        v4 w3 = *(const v4*)&W1[(128 + kk + 3) * 128 + jq];
        #pragma unroll
        for (int e = 0; e < EPG; ++e) {
            const v4 x = *(const v4*)&enc_h[(size_t)(b0 + e) * 128 + kk];
            hp[e] += splat4(x.x) * w0 + splat4(x.y) * w1
                   + splat4(x.z) * w2 + splat4(x.w) * w3;
        }
    }
    // fold -(mean*inv_std) @ W1env into hpre (s_w1e already has inv_std)
    #pragma unroll
    for (int k = 0; k < 8; ++k) {
        const float mk = scaler_mean[k];
        const v4 w = *(const v4*)&s_w1e[k * 128 + jq];
        #pragma unroll
        for (int e = 0; e < EPG; ++e) hp[e] -= splat4(mk) * w;
    }

    // ---- carry init ----
    float ego_v[EPG], ego_a[EPG], ego_x[EPG], disp[EPG];
    #pragma unroll
    for (int e = 0; e < EPG; ++e) {
        const float* sr = idm_s + (size_t)(b0 + e) * 714;   // 51*14
        ego_v[e] = sr[0];
        ego_a[e] = sr[11];
        ego_x[e] = sr[3];
        disp[e]  = 0.0f;
    }

    float* out_disp = out;
    float* out_act  = out + NB * 51;
    float* out_fat  = out + NB * (51 + 50);
    float* out_mat  = out + NB * (51 + 100);
    if (sidx == 0) {
        #pragma unroll
        for (int e = 0; e < EPG; ++e) out_disp[(b0 + e) * 51] = 0.0f;
    }

    // prefetch t=0 scalars
    float c_fv[EPG], c_mv[EPG], c_fx[EPG], c_mx[EPG], c_fa[EPG], c_me[EPG];
    float c_m0[EPG], c_m1[EPG], c_m2[EPG];
    #pragma unroll
    for (int e = 0; e < EPG; ++e) {
        const float* sr = idm_s + (size_t)(b0 + e) * 714;
        const float* mr = merger_cs + (size_t)(b0 + e) * 150;
        c_fv[e] = sr[1];  c_mv[e] = sr[2];
        c_fx[e] = sr[4];  c_mx[e] = sr[5];
        c_fa[e] = sr[12]; c_me[e] = sr[13];
        c_m0[e] = mr[0];  c_m1[e] = mr[1]; c_m2[e] = mr[2];
    }

    for (int t = 0; t < NT; ++t) {
        float env[EPG][8], m0[EPG], m1[EPG], m2[EPG];
        float ef_dx[EPG], em_dx[EPG], ef_dv[EPG], em_dv[EPG];
        #pragma unroll
        for (int e = 0; e < EPG; ++e) {
            const float fv = c_fv[e], mv = c_mv[e], fx = c_fx[e], mx = c_mx[e];
            const float fa = c_fa[e], me = c_me[e];
            m0[e] = c_m0[e]; m1[e] = c_m1[e]; m2[e] = c_m2[e];
            ef_dx[e] = fx - ego_x[e];
            em_dx[e] = (mx - ego_x[e]) * me + (1.0f - me) * 100.0f;
            ef_dv[e] = ego_v[e] - fv;
            em_dv[e] = (ego_v[e] - mv) * me;
            env[e][0] = ego_a[e]; env[e][1] = fa;
            env[e][2] = ego_v[e]; env[e][3] = fv;
            env[e][4] = ef_dv[e]; env[e][5] = ef_dx[e];
            env[e][6] = em_dv[e]; env[e][7] = em_dx[e];
        }
        if (t + 1 < NT) {
            #pragma unroll
            for (int e = 0; e < EPG; ++e) {
                const float* sp = idm_s + (size_t)(b0 + e) * 714 + (t + 1) * 14;
                c_fv[e] = sp[1]; c_mv[e] = sp[2]; c_fx[e] = sp[4]; c_mx[e] = sp[5];
                c_fa[e] = sp[12]; c_me[e] = sp[13];
                const float* mp = merger_cs + (size_t)(b0 + e) * 150 + (t + 1) * 3;
                c_m0[e] = mp[0]; c_m1[e] = mp[1]; c_m2[e] = mp[2];
            }
        }

        // ---- layer 1: 8 env rows + 3 mc rows ----
        v4 h1[EPG];
        #pragma unroll
        for (int e = 0; e < EPG; ++e) h1[e] = hp[e];
        #pragma unroll
        for (int k = 0; k < 8; ++k) {
            const v4 w = *(const v4*)&s_w1e[k * 128 + jq];
            #pragma unroll
            for (int e = 0; e < EPG; ++e) h1[e] += splat4(env[e][k]) * w;
        }
        #pragma unroll
        for (int k = 0; k < 3; ++k) {
            const v4 w = *(const v4*)&s_w1m[k * 128 + jq];
            #pragma unroll
            for (int e = 0; e < EPG; ++e) {
                const float x = (k == 0) ? m0[e] : (k == 1) ? m1[e] : m2[e];
                h1[e] += splat4(x) * w;
            }
        }
        #pragma unroll
        for (int e = 0; e < EPG; ++e) {
            *(v4*)&s_pk[g][e][jq] = leaky4(h1[e]);
        }
        asm volatile("" ::: "memory");      // intra-wave DS in-order; block reorder

        // ---- layer 2: h2 = leaky(h1 @ W2 + b2), 4 cols x EPG elems per lane ----
        v4 acc[EPG];
        #pragma unroll
        for (int e = 0; e < EPG; ++e) acc[e] = splat4(0.0f);
        #pragma unroll 8
        for (int kk = 0; kk < 128; kk += 4) {
            const v4 w0 = *(const v4*)&s_w2[(kk + 0) * 128 + jq];
            const v4 w1 = *(const v4*)&s_w2[(kk + 1) * 128 + jq];
            const v4 w2 = *(const v4*)&s_w2[(kk + 2) * 128 + jq];
            const v4 w3 = *(const v4*)&s_w2[(kk + 3) * 128 + jq];
            #pragma unroll
            for (int e = 0; e < EPG; ++e) {
                const v4 he = *(const v4*)&s_pk[g][e][kk];   // group-uniform broadcast
                acc[e] += splat4(he.x) * w0 + splat4(he.y) * w1
                        + splat4(he.z) * w2 + splat4(he.w) * w3;
            }
        }

        // heads + per-elem dynamics
        #pragma unroll
        for (int e = 0; e < EPG; ++e) {
            const v4 h2 = leaky4(acc[e] + b2q);
            float fp = h2.x * wfq.x + h2.y * wfq.y + h2.z * wfq.z + h2.w * wfq.w;
            float mq = h2.x * wmq.x + h2.y * wmq.y + h2.z * wmq.z + h2.w * wmq.w;
            fp += __shfl_xor(fp, 1); fp += __shfl_xor(fp, 2);
            fp += __shfl_xor(fp, 4); fp += __shfl_xor(fp, 8); fp += __shfl_xor(fp, 16);
            mq += __shfl_xor(mq, 1); mq += __shfl_xor(mq, 2);
            mq += __shfl_xor(mq, 4); mq += __shfl_xor(mq, 8); mq += __shfl_xor(mq, 16);

            const float f_sc = fminf(fmaxf(fp + bfv, -20.0f), 20.0f);
            const float m_sc = fminf(fmaxf(mq + bmv, -20.0f), 20.0f);
            const float dsc = 5.0f * (f_sc - m_sc);
            float fatt;
            if (dsc >= 0.0f) { const float ex = __expf(-dsc); fatt = 1.0f / (1.0f + ex); }
            else             { const float ex = __expf(dsc);  fatt = ex / (1.0f + ex); }
            const float matt = 1.0f - fatt;

            const float efa = idm_act_f(ego_v[e], ef_dv[e], ef_dx[e],
                                        inv_v0[e], p_tg[e], p_jam[e], p_amax[e], inv_gd[e]);
            const float ema = idm_act_f(ego_v[e], em_dv[e], em_dx[e],
                                        inv_v0[e], p_tg[e], p_jam[e], p_amax[e], inv_gd[e]);
            const float a2n = fatt * efa + matt * ema;

            const float delta = ego_v[e] * 0.1f + 0.005f * a2n;
            disp[e]  += delta;
            ego_x[e] += delta;
            ego_v[e] += a2n * 0.1f;
            ego_a[e]  = a2n;

            if (sidx == 0) {
                const int b = b0 + e;
                out_disp[b * 51 + t + 1] = disp[e];
                out_act [b * 50 + t]     = a2n;
                out_fat [b * 50 + t]     = fatt;
                out_mat [b * 50 + t]     = matt;
            }
        }
    }
}

extern "C" void kernel_launch(void* const* d_in, const int* in_sizes, int n_in,
                              void* d_out, int out_size, void* d_ws, size_t ws_size,
                              hipStream_t stream) {
    (void)in_sizes; (void)n_in; (void)d_ws; (void)ws_size; (void)out_size;
    const float* idm_params  = (const float*)d_in[0];
    const float* proj_latent = (const float*)d_in[1];
    const float* enc_h       = (const float*)d_in[2];
    const float* idm_s       = (const float*)d_in[3];
    const float* merger_cs   = (const float*)d_in[4];
    const float* scaler_mean = (const float*)d_in[5];
    const float* scaler_var  = (const float*)d_in[6];
    const float* W1          = (const float*)d_in[7];
    const float* b1          = (const float*)d_in[8];
    const float* W2          = (const float*)d_in[9];
    const float* b2          = (const float*)d_in[10];
    const float* Wf          = (const float*)d_in[11];
    const float* bfp         = (const float*)d_in[12];
    const float* Wm          = (const float*)d_in[13];
    const float* bmp         = (const float*)d_in[14];

    idm_rollout_kernel<<<dim3(NB / (8 * EPG)), dim3(256), 0, stream>>>(
        idm_params, proj_latent, enc_h, idm_s, merger_cs,
        scaler_mean, scaler_var, W1, b1, W2, b2, Wf, bfp, Wm, bmp,
        (float*)d_out);
}

// Round 6
// 242.915 us; speedup vs baseline: 20.4278x; 1.4057x over previous
//
#include <hip/hip_runtime.h>

#define NB 8192
#define NT 50

typedef short short8 __attribute__((ext_vector_type(8)));
typedef float f32x4 __attribute__((ext_vector_type(4)));

__device__ __forceinline__ float leaky(float x) { return x > 0.0f ? x : 0.3f * x; }

__device__ __forceinline__ unsigned short bf16rn(float v) {
    unsigned int u = __float_as_uint(v);
    unsigned int r = u + 0x7FFFu + ((u >> 16) & 1u);
    return (unsigned short)(r >> 16);
}
__device__ __forceinline__ float bf16tof(unsigned short h) {
    return __uint_as_float(((unsigned int)h) << 16);
}

__device__ __forceinline__ float idm_act_f(float v, float dv, float dx,
                                           float inv_v0, float tg, float jam,
                                           float amax, float inv_gd) {
    dx = fminf(fmaxf(dx, 0.1f), 500.0f);
    float gap = tg * v + v * dv * inv_gd;
    float dg = jam + fmaxf(gap, 0.0f);
    float r = v * inv_v0;
    float r2 = r * r;
    float r4 = r2 * r2;
    float q = dg / dx;
    float act = amax * (1.0f - r4 - q * q);
    return fminf(fmaxf(act, -6.0f), 6.0f);
}

extern "C" __global__ __launch_bounds__(512, 1)
void idm_rollout_kernel(const float* __restrict__ idm_params,
                        const float* __restrict__ proj_latent,
                        const float* __restrict__ enc_h,
                        const float* __restrict__ idm_s,
                        const float* __restrict__ merger_cs,
                        const float* __restrict__ scaler_mean,
                        const float* __restrict__ scaler_var,
                        const float* __restrict__ W1,
                        const float* __restrict__ b1,
                        const float* __restrict__ W2,
                        const float* __restrict__ b2,
                        const float* __restrict__ Wf,
                        const float* __restrict__ bfp,
                        const float* __restrict__ Wm,
                        const float* __restrict__ bmp,
                        float* __restrict__ out)
{
    // h1 A-fragments, 3-level bf16 split: [mtile][kchunk][lvl][lane][e]
    __shared__ __align__(16) short s_a[2][4][3][64][8];    // 24 KB
    __shared__ __align__(16) float s_w1d[11][128];         // dyn W1 rows (env pre-scaled)
    __shared__ __align__(16) float s_env[32][12];          // env features + mc per elem
    __shared__ __align__(16) float s_part[8][2][16][2];    // per-wave head partials

    const int tid = threadIdx.x;       // 0..511
    const int w   = tid >> 6;          // wave 0..7  (= N-tile index)
    const int l   = tid & 63;
    const int lm  = l & 15;
    const int lq  = l >> 4;
    const int b0  = blockIdx.x * 32;

    // ---- stage dynamic W1 rows (256..266); env rows scaled by inv_std ----
    for (int idx = tid; idx < 11 * 128; idx += 512) {
        const int r = idx >> 7, c = idx & 127;
        float wv_ = W1[(256 + r) * 128 + c];
        if (r < 8) wv_ *= 1.0f / sqrtf(scaler_var[r]);
        s_w1d[r][c] = wv_;
    }

    // ---- this wave's B-fragments (ntile = w), 3-level split, registers ----
    short8 Bf0[4], Bf1[4], Bf2[4];
    #pragma unroll
    for (int kc = 0; kc < 4; ++kc) {
        #pragma unroll
        for (int e = 0; e < 8; ++e) {
            const float v = W2[(kc * 32 + lq * 8 + e) * 128 + (w * 16 + lm)];
            const unsigned short q0 = bf16rn(v);
            const float r1 = v - bf16tof(q0);
            const unsigned short q1 = bf16rn(r1);
            const float r2 = r1 - bf16tof(q1);
            Bf0[kc][e] = (short)q0;
            Bf1[kc][e] = (short)q1;
            Bf2[kc][e] = (short)bf16rn(r2);
        }
    }

    // ---- per-elem dynamics state (threads 0..31) ----
    float ego_v_r = 0, ego_a_r = 0, ego_x_r = 0, disp_r = 0;
    float ef_dv_r = 0, ef_dx_r = 0, em_dv_r = 0, em_dx_r = 0;
    float pinv_v0 = 0, ptg = 0, pjam = 0, pamax = 0, pinv_gd = 0;

    float* out_disp = out;
    float* out_act  = out + NB * 51;
    float* out_fat  = out + NB * (51 + 50);
    float* out_mat  = out + NB * (51 + 100);

    if (tid < 32) {
        const int b = b0 + tid;
        const float* sr = idm_s + (size_t)b * 714;     // 51*14
        const float* mr = merger_cs + (size_t)b * 150;
        ego_v_r = sr[0]; ego_a_r = sr[11]; ego_x_r = sr[3]; disp_r = 0.0f;
        const float fv0 = sr[1], mv0 = sr[2], fx0 = sr[4], mx0 = sr[5];
        const float fa0 = sr[12], me0 = sr[13];
        ef_dx_r = fx0 - ego_x_r;
        em_dx_r = (mx0 - ego_x_r) * me0 + (1.0f - me0) * 100.0f;
        ef_dv_r = ego_v_r - fv0;
        em_dv_r = (ego_v_r - mv0) * me0;
        s_env[tid][0] = ego_a_r; s_env[tid][1] = fa0;
        s_env[tid][2] = ego_v_r; s_env[tid][3] = fv0;
        s_env[tid][4] = ef_dv_r; s_env[tid][5] = ef_dx_r;
        s_env[tid][6] = em_dv_r; s_env[tid][7] = em_dx_r;
        s_env[tid][8] = mr[0]; s_env[tid][9] = mr[1]; s_env[tid][10] = mr[2];
        s_env[tid][11] = 0.0f;
        out_disp[b * 51] = 0.0f;

        const float v0 = idm_params[b * 5 + 0];
        ptg   = idm_params[b * 5 + 1];
        pjam  = idm_params[b * 5 + 2];
        pamax = idm_params[b * 5 + 3];
        const float amin = idm_params[b * 5 + 4];
        pinv_v0 = 1.0f / v0;
        pinv_gd = 1.0f / (2.0f * sqrtf(pamax * amin));
    }
    __syncthreads();

    // ---- phase-A geometry: wave w computes h1 for mtile=w&1, kchunk=w>>1 ----
    const int mt  = w & 1;
    const int kca = w >> 1;
    const int k0  = kca * 32 + lq * 8;
    const int bm  = b0 + mt * 16 + lm;

    // ---- hpre: time-invariant layer-1 preactivation (m=bm, cols k0..k0+7) ----
    float hpv[8];
    {
        const f32x4 bA = *(const f32x4*)&b1[k0];
        const f32x4 bB = *(const f32x4*)&b1[k0 + 4];
        hpv[0] = bA.x; hpv[1] = bA.y; hpv[2] = bA.z; hpv[3] = bA.w;
        hpv[4] = bB.x; hpv[5] = bB.y; hpv[6] = bB.z; hpv[7] = bB.w;
        const float* xl0 = proj_latent + (size_t)bm * 128;
        const float* xl1 = enc_h + (size_t)bm * 128;
        #pragma unroll 4
        for (int r = 0; r < 128; ++r) {
            const float x = xl0[r];
            const f32x4 wA = *(const f32x4*)&W1[r * 128 + k0];
            const f32x4 wB = *(const f32x4*)&W1[r * 128 + k0 + 4];
            hpv[0] += x * wA.x; hpv[1] += x * wA.y; hpv[2] += x * wA.z; hpv[3] += x * wA.w;
            hpv[4] += x * wB.x; hpv[5] += x * wB.y; hpv[6] += x * wB.z; hpv[7] += x * wB.w;
        }
        #pragma unroll 4
        for (int r = 0; r < 128; ++r) {
            const float x = xl1[r];
            const f32x4 wA = *(const f32x4*)&W1[(128 + r) * 128 + k0];
            const f32x4 wB = *(const f32x4*)&W1[(128 + r) * 128 + k0 + 4];
            hpv[0] += x * wA.x; hpv[1] += x * wA.y; hpv[2] += x * wA.z; hpv[3] += x * wA.w;
            hpv[4] += x * wB.x; hpv[5] += x * wB.y; hpv[6] += x * wB.z; hpv[7] += x * wB.w;
        }
        #pragma unroll
        for (int r = 0; r < 8; ++r) {   // fold -(mean*inv_std)@W1env
            const float mk = scaler_mean[r];
            const f32x4 wA = *(const f32x4*)&s_w1d[r][k0];
            const f32x4 wB = *(const f32x4*)&s_w1d[r][k0 + 4];
            hpv[0] -= mk * wA.x; hpv[1] -= mk * wA.y; hpv[2] -= mk * wA.z; hpv[3] -= mk * wA.w;
            hpv[4] -= mk * wB.x; hpv[5] -= mk * wB.y; hpv[6] -= mk * wB.z; hpv[7] -= mk * wB.w;
        }
    }

    // ---- head constants for this wave's N-tile ----
    const float b2v = b2[w * 16 + lm];
    const float wfv = Wf[w * 16 + lm];
    const float wmv = Wm[w * 16 + lm];
    const float bfv = bfp[0];
    const float bmv = bmp[0];

    for (int t = 0; t < NT; ++t) {
        // ---- prefetch next-step exogenous scalars (threads 0..31) ----
        float nf_fv = 0, nf_mv = 0, nf_fx = 0, nf_mx = 0, nf_fa = 0, nf_me = 0;
        float nf_m0 = 0, nf_m1 = 0, nf_m2 = 0;
        if (tid < 32 && t + 1 < NT) {
            const float* sp = idm_s + (size_t)(b0 + tid) * 714 + (t + 1) * 14;
            nf_fv = sp[1]; nf_mv = sp[2]; nf_fx = sp[4]; nf_mx = sp[5];
            nf_fa = sp[12]; nf_me = sp[13];
            const float* mp = merger_cs + (size_t)(b0 + tid) * 150 + (t + 1) * 3;
            nf_m0 = mp[0]; nf_m1 = mp[1]; nf_m2 = mp[2];
        }

        // ---- phase A: layer-1 (m=bm, k=k0..k0+7), 3-level A-fragments ----
        float ev[11];
        {
            const f32x4 e0 = *(const f32x4*)&s_env[mt * 16 + lm][0];
            const f32x4 e1 = *(const f32x4*)&s_env[mt * 16 + lm][4];
            const f32x4 e2 = *(const f32x4*)&s_env[mt * 16 + lm][8];
            ev[0] = e0.x; ev[1] = e0.y; ev[2] = e0.z; ev[3] = e0.w;
            ev[4] = e1.x; ev[5] = e1.y; ev[6] = e1.z; ev[7] = e1.w;
            ev[8] = e2.x; ev[9] = e2.y; ev[10] = e2.z;
        }
        float h[8];
        #pragma unroll
        for (int e = 0; e < 8; ++e) h[e] = hpv[e];
        #pragma unroll
        for (int r = 0; r < 11; ++r) {
            const f32x4 wA = *(const f32x4*)&s_w1d[r][k0];
            const f32x4 wB = *(const f32x4*)&s_w1d[r][k0 + 4];
            const float x = ev[r];
            h[0] += x * wA.x; h[1] += x * wA.y; h[2] += x * wA.z; h[3] += x * wA.w;
            h[4] += x * wB.x; h[5] += x * wB.y; h[6] += x * wB.z; h[7] += x * wB.w;
        }
        short8 A0, A1, A2;
        #pragma unroll
        for (int e = 0; e < 8; ++e) {
            const float v = leaky(h[e]);
            const unsigned short q0 = bf16rn(v);
            const float r1 = v - bf16tof(q0);
            const unsigned short q1 = bf16rn(r1);
            const float r2 = r1 - bf16tof(q1);
            A0[e] = (short)q0;
            A1[e] = (short)q1;
            A2[e] = (short)bf16rn(r2);
        }
        *(short8*)&s_a[mt][kca][0][l][0] = A0;
        *(short8*)&s_a[mt][kca][1][l][0] = A1;
        *(short8*)&s_a[mt][kca][2][l][0] = A2;

        __syncthreads();   // B1: A-fragments visible

        // ---- phase B: 6-term split MFMA, 2 M-tiles, this wave's N-tile ----
        f32x4 aA0 = {0,0,0,0}, aB0 = {0,0,0,0}, aC0 = {0,0,0,0};
        f32x4 aA1 = {0,0,0,0}, aB1 = {0,0,0,0}, aC1 = {0,0,0,0};
        #pragma unroll
        for (int kc = 0; kc < 4; ++kc) {
            const short8 x00 = *(const short8*)&s_a[0][kc][0][l][0];
            const short8 x01 = *(const short8*)&s_a[0][kc][1][l][0];
            const short8 x02 = *(const short8*)&s_a[0][kc][2][l][0];
            const short8 x10 = *(const short8*)&s_a[1][kc][0][l][0];
            const short8 x11 = *(const short8*)&s_a[1][kc][1][l][0];
            const short8 x12 = *(const short8*)&s_a[1][kc][2][l][0];
            aA0 = __builtin_amdgcn_mfma_f32_16x16x32_bf16(x00, Bf0[kc], aA0, 0, 0, 0);
            aB0 = __builtin_amdgcn_mfma_f32_16x16x32_bf16(x00, Bf1[kc], aB0, 0, 0, 0);
            aB0 = __builtin_amdgcn_mfma_f32_16x16x32_bf16(x01, Bf0[kc], aB0, 0, 0, 0);
            aC0 = __builtin_amdgcn_mfma_f32_16x16x32_bf16(x01, Bf1[kc], aC0, 0, 0, 0);
            aC0 = __builtin_amdgcn_mfma_f32_16x16x32_bf16(x00, Bf2[kc], aC0, 0, 0, 0);
            aC0 = __builtin_amdgcn_mfma_f32_16x16x32_bf16(x02, Bf0[kc], aC0, 0, 0, 0);
            aA1 = __builtin_amdgcn_mfma_f32_16x16x32_bf16(x10, Bf0[kc], aA1, 0, 0, 0);
            aB1 = __builtin_amdgcn_mfma_f32_16x16x32_bf16(x10, Bf1[kc], aB1, 0, 0, 0);
            aB1 = __builtin_amdgcn_mfma_f32_16x16x32_bf16(x11, Bf0[kc], aB1, 0, 0, 0);
            aC1 = __builtin_amdgcn_mfma_f32_16x16x32_bf16(x11, Bf1[kc], aC1, 0, 0, 0);
            aC1 = __builtin_amdgcn_mfma_f32_16x16x32_bf16(x10, Bf2[kc], aC1, 0, 0, 0);
            aC1 = __builtin_amdgcn_mfma_f32_16x16x32_bf16(x12, Bf0[kc], aC1, 0, 0, 0);
        }

        // heads: D[m][n]: m = lq*4+r (row), n = w*16+lm (col)
        #pragma unroll
        for (int mtc = 0; mtc < 2; ++mtc) {
            #pragma unroll
            for (int r = 0; r < 4; ++r) {
                const float s = (mtc == 0 ? aA0[r] + aB0[r] + aC0[r]
                                          : aA1[r] + aB1[r] + aC1[r]) + b2v;
                const float h2 = leaky(s);
                float f = h2 * wfv;
                float mqq = h2 * wmv;
                f += __shfl_xor(f, 1); f += __shfl_xor(f, 2);
                f += __shfl_xor(f, 4); f += __shfl_xor(f, 8);
                mqq += __shfl_xor(mqq, 1); mqq += __shfl_xor(mqq, 2);
                mqq += __shfl_xor(mqq, 4); mqq += __shfl_xor(mqq, 8);
                if (lm == 0) {
                    s_part[w][mtc][lq * 4 + r][0] = f;
                    s_part[w][mtc][lq * 4 + r][1] = mqq;
                }
            }
        }

        __syncthreads();   // B2: head partials visible

        // ---- phase C: per-elem scores + dynamics (threads 0..31) ----
        if (tid < 32) {
            const int mL = tid & 15;
            const int mtc = tid >> 4;
            const int b = b0 + tid;
            float fsum = bfv, msum = bmv;
            #pragma unroll
            for (int ww = 0; ww < 8; ++ww) {
                fsum += s_part[ww][mtc][mL][0];
                msum += s_part[ww][mtc][mL][1];
            }
            const float f_sc = fminf(fmaxf(fsum, -20.0f), 20.0f);
            const float m_sc = fminf(fmaxf(msum, -20.0f), 20.0f);
            const float dsc = 5.0f * (f_sc - m_sc);
            float fatt;
            if (dsc >= 0.0f) { const float ex = __expf(-dsc); fatt = 1.0f / (1.0f + ex); }
            else             { const float ex = __expf(dsc);  fatt = ex / (1.0f + ex); }
            const float matt = 1.0f - fatt;

            const float efa = idm_act_f(ego_v_r, ef_dv_r, ef_dx_r,
                                        pinv_v0, ptg, pjam, pamax, pinv_gd);
            const float ema = idm_act_f(ego_v_r, em_dv_r, em_dx_r,
                                        pinv_v0, ptg, pjam, pamax, pinv_gd);
            const float a2n = fatt * efa + matt * ema;

            const float delta = ego_v_r * 0.1f + 0.005f * a2n;
            disp_r  += delta;
            ego_x_r += delta;
            ego_v_r += a2n * 0.1f;
            ego_a_r  = a2n;

            out_disp[b * 51 + t + 1] = disp_r;
            out_act [b * 50 + t]     = a2n;
            out_fat [b * 50 + t]     = fatt;
            out_mat [b * 50 + t]     = matt;

            if (t + 1 < NT) {
                ef_dx_r = nf_fx - ego_x_r;
                em_dx_r = (nf_mx - ego_x_r) * nf_me + (1.0f - nf_me) * 100.0f;
                ef_dv_r = ego_v_r - nf_fv;
                em_dv_r = (ego_v_r - nf_mv) * nf_me;
                s_env[tid][0] = ego_a_r; s_env[tid][1] = nf_fa;
                s_env[tid][2] = ego_v_r; s_env[tid][3] = nf_fv;
                s_env[tid][4] = ef_dv_r; s_env[tid][5] = ef_dx_r;
                s_env[tid][6] = em_dv_r; s_env[tid][7] = em_dx_r;
                s_env[tid][8] = nf_m0; s_env[tid][9] = nf_m1; s_env[tid][10] = nf_m2;
            }
        }

        __syncthreads();   // B3: env for next step visible
    }
}

extern "C" void kernel_launch(void* const* d_in, const int* in_sizes, int n_in,
                              void* d_out, int out_size, void* d_ws, size_t ws_size,
                              hipStream_t stream) {
    (void)in_sizes; (void)n_in; (void)d_ws; (void)ws_size; (void)out_size;
    const float* idm_params  = (const float*)d_in[0];
    const float* proj_latent = (const float*)d_in[1];
    const float* enc_h       = (const float*)d_in[2];
    const float* idm_s       = (const float*)d_in[3];
    const float* merger_cs   = (const float*)d_in[4];
    const float* scaler_mean = (const float*)d_in[5];
    const float* scaler_var  = (const float*)d_in[6];
    const float* W1          = (const float*)d_in[7];
    const float* b1          = (const float*)d_in[8];
    const float* W2          = (const float*)d_in[9];
    const float* b2          = (const float*)d_in[10];
    const float* Wf          = (const float*)d_in[11];
    const float* bfp         = (const float*)d_in[12];
    const float* Wm          = (const float*)d_in[13];
    const float* bmp         = (const float*)d_in[14];

    idm_rollout_kernel<<<dim3(NB / 32), dim3(512), 0, stream>>>(
        idm_params, proj_latent, enc_h, idm_s, merger_cs,
        scaler_mean, scaler_var, W1, b1, W2, b2, Wf, bfp, Wm, bmp,
        (float*)d_out);
}

// Round 7
// 238.329 us; speedup vs baseline: 20.8209x; 1.0192x over previous
//
#include <hip/hip_runtime.h>

#define NB 8192
#define NT 50

typedef short short8 __attribute__((ext_vector_type(8)));
typedef float f32x4 __attribute__((ext_vector_type(4)));

__device__ __forceinline__ float leaky(float x) { return x > 0.0f ? x : 0.3f * x; }

__device__ __forceinline__ unsigned short bf16rn(float v) {
    unsigned int u = __float_as_uint(v);
    unsigned int r = u + 0x7FFFu + ((u >> 16) & 1u);
    return (unsigned short)(r >> 16);
}
__device__ __forceinline__ float bf16tof(unsigned short h) {
    return __uint_as_float(((unsigned int)h) << 16);
}

__device__ __forceinline__ float idm_act_f(float v, float dv, float dx,
                                           float inv_v0, float tg, float jam,
                                           float amax, float inv_gd) {
    dx = fminf(fmaxf(dx, 0.1f), 500.0f);
    float gap = tg * v + v * dv * inv_gd;
    float dg = jam + fmaxf(gap, 0.0f);
    float r = v * inv_v0;
    float r2 = r * r;
    float r4 = r2 * r2;
    float q = dg / dx;
    float act = amax * (1.0f - r4 - q * q);
    return fminf(fmaxf(act, -6.0f), 6.0f);
}

extern "C" __global__ __launch_bounds__(256, 2)
void idm_rollout_kernel(const float* __restrict__ idm_params,
                        const float* __restrict__ proj_latent,
                        const float* __restrict__ enc_h,
                        const float* __restrict__ idm_s,
                        const float* __restrict__ merger_cs,
                        const float* __restrict__ scaler_mean,
                        const float* __restrict__ scaler_var,
                        const float* __restrict__ W1,
                        const float* __restrict__ b1,
                        const float* __restrict__ W2,
                        const float* __restrict__ b2,
                        const float* __restrict__ Wf,
                        const float* __restrict__ bfp,
                        const float* __restrict__ Wm,
                        const float* __restrict__ bmp,
                        float* __restrict__ out)
{
    // h1 A-fragments, 3-level bf16 split: [kchunk][lvl][lane][e]
    __shared__ __align__(16) short s_a[4][3][64][8];       // 12 KB
    __shared__ __align__(16) float s_w1d[11][128];         // dyn W1 rows (env pre-scaled)
    __shared__ __align__(16) float s_part[8][16][2];       // per-ntile head partials

    const int tid = threadIdx.x;       // 0..255
    const int w   = tid >> 6;          // wave 0..3 (= kchunk in phase A)
    const int l   = tid & 63;
    const int lm  = l & 15;            // elem index / n-col within tile
    const int lq  = l >> 4;
    const int b0  = blockIdx.x * 16;
    const int bm  = b0 + lm;           // this lane's batch element

    // ---- stage dynamic W1 rows (256..266); env rows scaled by inv_std ----
    for (int idx = tid; idx < 11 * 128; idx += 256) {
        const int r = idx >> 7, c = idx & 127;
        float wv_ = W1[(256 + r) * 128 + c];
        if (r < 8) wv_ *= 1.0f / sqrtf(scaler_var[r]);
        s_w1d[r][c] = wv_;
    }

    // ---- this wave's B-fragments (ntiles 2w, 2w+1), 3-level, registers ----
    const int nt0 = w * 2, nt1 = w * 2 + 1;
    short8 B00[4], B01[4], B02[4];   // ntile nt0, levels 0..2
    short8 B10[4], B11[4], B12[4];   // ntile nt1
    #pragma unroll
    for (int kc = 0; kc < 4; ++kc) {
        #pragma unroll
        for (int e = 0; e < 8; ++e) {
            const int krow = kc * 32 + lq * 8 + e;
            {
                const float v = W2[krow * 128 + (nt0 * 16 + lm)];
                const unsigned short q0 = bf16rn(v);
                const float r1 = v - bf16tof(q0);
                const unsigned short q1 = bf16rn(r1);
                const float r2 = r1 - bf16tof(q1);
                B00[kc][e] = (short)q0; B01[kc][e] = (short)q1; B02[kc][e] = (short)bf16rn(r2);
            }
            {
                const float v = W2[krow * 128 + (nt1 * 16 + lm)];
                const unsigned short q0 = bf16rn(v);
                const float r1 = v - bf16tof(q0);
                const unsigned short q1 = bf16rn(r1);
                const float r2 = r1 - bf16tof(q1);
                B10[kc][e] = (short)q0; B11[kc][e] = (short)q1; B12[kc][e] = (short)bf16rn(r2);
            }
        }
    }

    // ---- per-lane dynamics state for elem bm (redundant x16) ----
    float ego_v_r, ego_a_r, ego_x_r, disp_r;
    float ef_dv_r, ef_dx_r, em_dv_r, em_dx_r;
    float c_fa, c_fv, c_m0, c_m1, c_m2;
    {
        const float* sr = idm_s + (size_t)bm * 714;     // 51*14
        const float* mr = merger_cs + (size_t)bm * 150;
        ego_v_r = sr[0]; ego_a_r = sr[11]; ego_x_r = sr[3]; disp_r = 0.0f;
        const float fv0 = sr[1], mv0 = sr[2], fx0 = sr[4], mx0 = sr[5];
        c_fa = sr[12];
        const float me0 = sr[13];
        c_fv = fv0;
        ef_dx_r = fx0 - ego_x_r;
        em_dx_r = (mx0 - ego_x_r) * me0 + (1.0f - me0) * 100.0f;
        ef_dv_r = ego_v_r - fv0;
        em_dv_r = (ego_v_r - mv0) * me0;
        c_m0 = mr[0]; c_m1 = mr[1]; c_m2 = mr[2];
    }
    const float p_v0   = idm_params[bm * 5 + 0];
    const float ptg    = idm_params[bm * 5 + 1];
    const float pjam   = idm_params[bm * 5 + 2];
    const float pamax  = idm_params[bm * 5 + 3];
    const float pamin  = idm_params[bm * 5 + 4];
    const float pinv_v0 = 1.0f / p_v0;
    const float pinv_gd = 1.0f / (2.0f * sqrtf(pamax * pamin));

    float* out_disp = out;
    float* out_act  = out + NB * 51;
    float* out_fat  = out + NB * (51 + 50);
    float* out_mat  = out + NB * (51 + 100);
    if (tid < 16) out_disp[bm * 51] = 0.0f;

    __syncthreads();   // s_w1d staged

    // ---- hpre: time-invariant layer-1 preactivation (m=bm, cols k0..k0+7) ----
    const int k0 = w * 32 + lq * 8;
    float hpv[8];
    {
        const f32x4 bA = *(const f32x4*)&b1[k0];
        const f32x4 bB = *(const f32x4*)&b1[k0 + 4];
        hpv[0] = bA.x; hpv[1] = bA.y; hpv[2] = bA.z; hpv[3] = bA.w;
        hpv[4] = bB.x; hpv[5] = bB.y; hpv[6] = bB.z; hpv[7] = bB.w;
        const float* xl0 = proj_latent + (size_t)bm * 128;
        const float* xl1 = enc_h + (size_t)bm * 128;
        #pragma unroll 4
        for (int r = 0; r < 128; ++r) {
            const float x = xl0[r];
            const f32x4 wA = *(const f32x4*)&W1[r * 128 + k0];
            const f32x4 wB = *(const f32x4*)&W1[r * 128 + k0 + 4];
            hpv[0] += x * wA.x; hpv[1] += x * wA.y; hpv[2] += x * wA.z; hpv[3] += x * wA.w;
            hpv[4] += x * wB.x; hpv[5] += x * wB.y; hpv[6] += x * wB.z; hpv[7] += x * wB.w;
        }
        #pragma unroll 4
        for (int r = 0; r < 128; ++r) {
            const float x = xl1[r];
            const f32x4 wA = *(const f32x4*)&W1[(128 + r) * 128 + k0];
            const f32x4 wB = *(const f32x4*)&W1[(128 + r) * 128 + k0 + 4];
            hpv[0] += x * wA.x; hpv[1] += x * wA.y; hpv[2] += x * wA.z; hpv[3] += x * wA.w;
            hpv[4] += x * wB.x; hpv[5] += x * wB.y; hpv[6] += x * wB.z; hpv[7] += x * wB.w;
        }
        #pragma unroll
        for (int r = 0; r < 8; ++r) {   // fold -(mean*inv_std)@W1env
            const float mk = scaler_mean[r];
            const f32x4 wA = *(const f32x4*)&s_w1d[r][k0];
            const f32x4 wB = *(const f32x4*)&s_w1d[r][k0 + 4];
            hpv[0] -= mk * wA.x; hpv[1] -= mk * wA.y; hpv[2] -= mk * wA.z; hpv[3] -= mk * wA.w;
            hpv[4] -= mk * wB.x; hpv[5] -= mk * wB.y; hpv[6] -= mk * wB.z; hpv[7] -= mk * wB.w;
        }
    }

    // ---- head constants for this wave's two N-tiles ----
    const float b2v0 = b2[nt0 * 16 + lm];
    const float b2v1 = b2[nt1 * 16 + lm];
    const float wfv0 = Wf[nt0 * 16 + lm];
    const float wfv1 = Wf[nt1 * 16 + lm];
    const float wmv0 = Wm[nt0 * 16 + lm];
    const float wmv1 = Wm[nt1 * 16 + lm];
    const float bfv = bfp[0];
    const float bmv = bmp[0];

    for (int t = 0; t < NT; ++t) {
        // ---- prefetch next-step exogenous scalars (all lanes, own elem) ----
        float nf_fv = 0, nf_mv = 0, nf_fx = 0, nf_mx = 0, nf_fa = 0, nf_me = 0;
        float nf_m0 = 0, nf_m1 = 0, nf_m2 = 0;
        if (t + 1 < NT) {
            const float* sp = idm_s + (size_t)bm * 714 + (t + 1) * 14;
            nf_fv = sp[1]; nf_mv = sp[2]; nf_fx = sp[4]; nf_mx = sp[5];
            nf_fa = sp[12]; nf_me = sp[13];
            const float* mp = merger_cs + (size_t)bm * 150 + (t + 1) * 3;
            nf_m0 = mp[0]; nf_m1 = mp[1]; nf_m2 = mp[2];
        }

        // ---- phase A: layer-1 (m=bm, k=k0..k0+7), 3-level A-fragments ----
        float ev[11];
        ev[0] = ego_a_r; ev[1] = c_fa;    ev[2] = ego_v_r; ev[3] = c_fv;
        ev[4] = ef_dv_r; ev[5] = ef_dx_r; ev[6] = em_dv_r; ev[7] = em_dx_r;
        ev[8] = c_m0;    ev[9] = c_m1;    ev[10] = c_m2;
        float h[8];
        #pragma unroll
        for (int e = 0; e < 8; ++e) h[e] = hpv[e];
        #pragma unroll
        for (int r = 0; r < 11; ++r) {
            const f32x4 wA = *(const f32x4*)&s_w1d[r][k0];
            const f32x4 wB = *(const f32x4*)&s_w1d[r][k0 + 4];
            const float x = ev[r];
            h[0] += x * wA.x; h[1] += x * wA.y; h[2] += x * wA.z; h[3] += x * wA.w;
            h[4] += x * wB.x; h[5] += x * wB.y; h[6] += x * wB.z; h[7] += x * wB.w;
        }
        short8 A0, A1, A2;
        #pragma unroll
        for (int e = 0; e < 8; ++e) {
            const float v = leaky(h[e]);
            const unsigned short q0 = bf16rn(v);
            const float r1 = v - bf16tof(q0);
            const unsigned short q1 = bf16rn(r1);
            const float r2 = r1 - bf16tof(q1);
            A0[e] = (short)q0; A1[e] = (short)q1; A2[e] = (short)bf16rn(r2);
        }
        *(short8*)&s_a[w][0][l][0] = A0;
        *(short8*)&s_a[w][1][l][0] = A1;
        *(short8*)&s_a[w][2][l][0] = A2;

        __syncthreads();   // B1: A-fragments visible

        // ---- phase B: 6-term split MFMA for ntiles nt0, nt1 ----
        f32x4 aA0 = {0,0,0,0}, aB0 = {0,0,0,0}, aC0 = {0,0,0,0};
        f32x4 aA1 = {0,0,0,0}, aB1 = {0,0,0,0}, aC1 = {0,0,0,0};
        #pragma unroll
        for (int kc = 0; kc < 4; ++kc) {
            const short8 x0 = *(const short8*)&s_a[kc][0][l][0];
            const short8 x1 = *(const short8*)&s_a[kc][1][l][0];
            const short8 x2 = *(const short8*)&s_a[kc][2][l][0];
            aA0 = __builtin_amdgcn_mfma_f32_16x16x32_bf16(x0, B00[kc], aA0, 0, 0, 0);
            aB0 = __builtin_amdgcn_mfma_f32_16x16x32_bf16(x0, B01[kc], aB0, 0, 0, 0);
            aB0 = __builtin_amdgcn_mfma_f32_16x16x32_bf16(x1, B00[kc], aB0, 0, 0, 0);
            aC0 = __builtin_amdgcn_mfma_f32_16x16x32_bf16(x1, B01[kc], aC0, 0, 0, 0);
            aC0 = __builtin_amdgcn_mfma_f32_16x16x32_bf16(x0, B02[kc], aC0, 0, 0, 0);
            aC0 = __builtin_amdgcn_mfma_f32_16x16x32_bf16(x2, B00[kc], aC0, 0, 0, 0);
            aA1 = __builtin_amdgcn_mfma_f32_16x16x32_bf16(x0, B10[kc], aA1, 0, 0, 0);
            aB1 = __builtin_amdgcn_mfma_f32_16x16x32_bf16(x0, B11[kc], aB1, 0, 0, 0);
            aB1 = __builtin_amdgcn_mfma_f32_16x16x32_bf16(x1, B10[kc], aB1, 0, 0, 0);
            aC1 = __builtin_amdgcn_mfma_f32_16x16x32_bf16(x1, B11[kc], aC1, 0, 0, 0);
            aC1 = __builtin_amdgcn_mfma_f32_16x16x32_bf16(x0, B12[kc], aC1, 0, 0, 0);
            aC1 = __builtin_amdgcn_mfma_f32_16x16x32_bf16(x2, B10[kc], aC1, 0, 0, 0);
        }

        // heads: D[m][n], m = lq*4+r, n = nt*16+lm; reduce over lm (n-cols)
        #pragma unroll
        for (int r = 0; r < 4; ++r) {
            const float h2a = leaky(aA0[r] + aB0[r] + aC0[r] + b2v0);
            const float h2b = leaky(aA1[r] + aB1[r] + aC1[r] + b2v1);
            float f0 = h2a * wfv0, m0s = h2a * wmv0;
            float f1 = h2b * wfv1, m1s = h2b * wmv1;
            f0 += __shfl_xor(f0, 1); f0 += __shfl_xor(f0, 2);
            f0 += __shfl_xor(f0, 4); f0 += __shfl_xor(f0, 8);
            m0s += __shfl_xor(m0s, 1); m0s += __shfl_xor(m0s, 2);
            m0s += __shfl_xor(m0s, 4); m0s += __shfl_xor(m0s, 8);
            f1 += __shfl_xor(f1, 1); f1 += __shfl_xor(f1, 2);
            f1 += __shfl_xor(f1, 4); f1 += __shfl_xor(f1, 8);
            m1s += __shfl_xor(m1s, 1); m1s += __shfl_xor(m1s, 2);
            m1s += __shfl_xor(m1s, 4); m1s += __shfl_xor(m1s, 8);
            if (lm == 0) {
                const int m = lq * 4 + r;
                s_part[nt0][m][0] = f0; s_part[nt0][m][1] = m0s;
                s_part[nt1][m][0] = f1; s_part[nt1][m][1] = m1s;
            }
        }

        __syncthreads();   // B2: head partials visible

        // ---- phase C: dynamics, redundant on all lanes (own elem bm) ----
        {
            float fsum = bfv, msum = bmv;
            #pragma unroll
            for (int nt = 0; nt < 8; ++nt) {
                fsum += s_part[nt][lm][0];
                msum += s_part[nt][lm][1];
            }
            const float f_sc = fminf(fmaxf(fsum, -20.0f), 20.0f);
            const float m_sc = fminf(fmaxf(msum, -20.0f), 20.0f);
            const float dsc = 5.0f * (f_sc - m_sc);
            float fatt;
            if (dsc >= 0.0f) { const float ex = __expf(-dsc); fatt = 1.0f / (1.0f + ex); }
            else             { const float ex = __expf(dsc);  fatt = ex / (1.0f + ex); }
            const float matt = 1.0f - fatt;

            const float efa = idm_act_f(ego_v_r, ef_dv_r, ef_dx_r,
                                        pinv_v0, ptg, pjam, pamax, pinv_gd);
            const float ema = idm_act_f(ego_v_r, em_dv_r, em_dx_r,
                                        pinv_v0, ptg, pjam, pamax, pinv_gd);
            const float a2n = fatt * efa + matt * ema;

            const float delta = ego_v_r * 0.1f + 0.005f * a2n;
            disp_r  += delta;
            ego_x_r += delta;
            ego_v_r += a2n * 0.1f;
            ego_a_r  = a2n;

            if (tid < 16) {
                out_disp[bm * 51 + t + 1] = disp_r;
                out_act [bm * 50 + t]     = a2n;
                out_fat [bm * 50 + t]     = fatt;
                out_mat [bm * 50 + t]     = matt;
            }

            if (t + 1 < NT) {
                ef_dx_r = nf_fx - ego_x_r;
                em_dx_r = (nf_mx - ego_x_r) * nf_me + (1.0f - nf_me) * 100.0f;
                ef_dv_r = ego_v_r - nf_fv;
                em_dv_r = (ego_v_r - nf_mv) * nf_me;
                c_fa = nf_fa; c_fv = nf_fv;
                c_m0 = nf_m0; c_m1 = nf_m1; c_m2 = nf_m2;
            }
        }
        // no third barrier: next phase A reads only registers + static LDS;
        // s_a rewrite is fenced by B1, s_part rewrite by B1+B2.
    }
}

extern "C" void kernel_launch(void* const* d_in, const int* in_sizes, int n_in,
                              void* d_out, int out_size, void* d_ws, size_t ws_size,
                              hipStream_t stream) {
    (void)in_sizes; (void)n_in; (void)d_ws; (void)ws_size; (void)out_size;
    const float* idm_params  = (const float*)d_in[0];
    const float* proj_latent = (const float*)d_in[1];
    const float* enc_h       = (const float*)d_in[2];
    const float* idm_s       = (const float*)d_in[3];
    const float* merger_cs   = (const float*)d_in[4];
    const float* scaler_mean = (const float*)d_in[5];
    const float* scaler_var  = (const float*)d_in[6];
    const float* W1          = (const float*)d_in[7];
    const float* b1          = (const float*)d_in[8];
    const float* W2          = (const float*)d_in[9];
    const float* b2          = (const float*)d_in[10];
    const float* Wf          = (const float*)d_in[11];
    const float* bfp         = (const float*)d_in[12];
    const float* Wm          = (const float*)d_in[13];
    const float* bmp         = (const float*)d_in[14];

    idm_rollout_kernel<<<dim3(NB / 16), dim3(256), 0, stream>>>(
        idm_params, proj_latent, enc_h, idm_s, merger_cs,
        scaler_mean, scaler_var, W1, b1, W2, b2, Wf, bfp, Wm, bmp,
        (float*)d_out);
}